// Round 1
// baseline (170.298 us; speedup 1.0000x reference)
//
#include <hip/hip_runtime.h>

// OptimizedLinear: out = x@W^T + bias - lr[:,None]*(x@G^T + bias_grad)
// B=4096, IN=OUT=2048, fp32 in/out. bf16 MFMA fused dual-accumulator GEMM.
//
// Round 8: structural move to T3+T4 (counted-vmcnt pipeline, raw s_barrier).
// Old loop was 1-phase: stage -> __syncthreads (vmcnt(0) drain!) -> compute.
// New: 256x128 tile, 8 waves, double-buffered LDS (128KB), per K-tile:
//   COMPUTE(cur); s_barrier; STAGE(cur, t+2); s_waitcnt vmcnt(8); s_barrier
// Loads for tile t+1 stay in flight across the barrier for the whole compute
// of tile t (m218: counted vs drain-0 = +38..73%). T5 setprio around MFMA
// cluster (role-split now exists). XCD-chunked bid swizzle: each XCD owns 2
// M-rows -> 2MB of A-panels L2-resident.
//
// Numerics identical to R7 (same granule walk / j-order / epilogue) ->
// absmax should remain 0.03125. Tripwire: WRITE_SIZE >> 40MB = acc spill.
// Lessons carried: swizzled granule layout measured conflict-free (R2-R7);
// per-wave scattered A-loads poison drains (R6); 256-reg acc spills (R5).

typedef unsigned short ushort_t;
typedef __attribute__((ext_vector_type(8))) short short8;       // 8 bf16 = 4 VGPR
typedef __attribute__((ext_vector_type(8))) unsigned short ushort8;
typedef __attribute__((ext_vector_type(4))) float f32x4;

#define GPTR(p) ((const __attribute__((address_space(1))) void*)(p))
#define LPTR(p) ((__attribute__((address_space(3))) void*)(p))

static constexpr int Kdim = 2048;
static constexpr int Ndim = 2048;
static constexpr int BK   = 64;
static constexpr int BM   = 256;
static constexpr int BN   = 128;
static constexpr int NT   = Kdim / BK;   // 32 K-tiles

__device__ __forceinline__ unsigned short f2bf(float f) {
    union { float f; unsigned u; } c; c.f = f;
    unsigned u = c.u;
    unsigned r = (u + 0x7fffu + ((u >> 16) & 1u)) >> 16;  // RNE
    return (unsigned short)r;
}

// One launch converts x (uX ushort8-units), W (uW), G (uW). Unit = 8 elems.
__global__ void cvt_all_kernel(const float* __restrict__ x,
                               const float* __restrict__ W,
                               const float* __restrict__ G,
                               ushort_t* __restrict__ xb,
                               ushort_t* __restrict__ wb,
                               ushort_t* __restrict__ gb,
                               int uX, int uW) {
    int u = blockIdx.x * blockDim.x + threadIdx.x;
    const float* src; ushort_t* dst;
    if (u < uX)            { src = x; dst = xb; }
    else if (u < uX + uW)  { src = W; dst = wb; u -= uX; }
    else                   { src = G; dst = gb; u -= uX + uW; }
    int i = u * 8;
    float4 a = *(const float4*)(src + i);
    float4 b = *(const float4*)(src + i + 4);
    ushort8 r;
    r[0] = f2bf(a.x); r[1] = f2bf(a.y); r[2] = f2bf(a.z); r[3] = f2bf(a.w);
    r[4] = f2bf(b.x); r[5] = f2bf(b.y); r[6] = f2bf(b.z); r[7] = f2bf(b.w);
    *(ushort8*)(dst + i) = r;
}

// ---- fused dual GEMM, 256x128 block tile, BK=64, 8 waves ----
// 512 threads = 8 waves (4 M x 2 N), each wave 64x64 = 4x4 MFMA tiles, dual acc.
// LDS tiles: A 256x64, W/G 128x64 bf16, all double-buffered: 128 KB total.
// Granule (row r, g=k/8) lives at slot r*8 + (g ^ (r&7)); swizzle applied on
// the GLOBAL fetch address (LDS dst is HW-forced to base + lane*16).
// Fragment read: addr = row*64 + ((j*4+quad) ^ (row&7))*8 -> conflict-free
// (measured 0 bank conflicts in R2-R7 with the identical layout).
__global__ __launch_bounds__(512, 2) void fused_gemm_kernel(
    const ushort_t* __restrict__ xb,   // [4096, 2048] bf16
    const ushort_t* __restrict__ wb,   // [2048, 2048] bf16
    const ushort_t* __restrict__ gb,   // [2048, 2048] bf16
    const float* __restrict__ bias,    // [2048]
    const float* __restrict__ bgrad,   // [2048]
    const float* __restrict__ lr,      // [4096]
    float* __restrict__ out)           // [4096, 2048] fp32
{
    __shared__ ushort_t As[2][BM * BK];  // 2 x 32 KB
    __shared__ ushort_t Ws[2][BN * BK];  // 2 x 16 KB
    __shared__ ushort_t Gs[2][BN * BK];  // 2 x 16 KB

    const int t    = threadIdx.x;
    const int wave = t >> 6;
    const int lane = t & 63;
    const int wm   = (wave >> 1) * 64;   // 0,64,128,192
    const int wn   = (wave & 1) * 64;    // 0,64

    // XCD-chunked swizzle: 256 blocks, 8 XCDs, 32 blocks/XCD = 2 by-rows x 16 bx.
    // bid%8 = XCD (round-robin dispatch assumption); bijective 8x32 remap.
    const int bid = blockIdx.y * 16 + blockIdx.x;
    const int swz = (bid & 7) * 32 + (bid >> 3);
    const int by  = swz >> 4;   // M tile (0..15)
    const int bx  = swz & 15;   // N tile (0..15)

    const int fr   = lane & 15;    // fragment row
    const int quad = lane >> 4;    // k-granule select (0..3)

    f32x4 accB[4][4] = {};
    f32x4 accP[4][4] = {};

    // --- staging addressing ---
    // A: 2048 slots of 16B (4 issues/thread). W/G: 1024 slots (2 issues each).
    // slot s: row = s>>3, fetched granule q' = (s&7) ^ (row&7)
    const ushort_t* gA[4]; int dA[4];
#pragma unroll
    for (int i = 0; i < 4; ++i) {
        int s   = i * 512 + t;
        int row = s >> 3;
        int q   = ((s & 7) ^ (row & 7)) * 8;
        gA[i] = xb + (size_t)(by * BM + row) * Kdim + q;
        dA[i] = (i * 512 + wave * 64) * 8;   // wave-uniform base; HW adds lane*16B
    }
    const ushort_t* gW[2]; const ushort_t* gG[2]; int dW[2];
#pragma unroll
    for (int i = 0; i < 2; ++i) {
        int s   = i * 512 + t;
        int row = s >> 3;
        int q   = ((s & 7) ^ (row & 7)) * 8;
        gW[i] = wb + (size_t)(bx * BN + row) * Kdim + q;
        gG[i] = gb + (size_t)(bx * BN + row) * Kdim + q;
        dW[i] = (i * 512 + wave * 64) * 8;
    }

    // 8 global_load_lds per thread per K-tile (4 A + 2 W + 2 G)
#define STAGE(B, K0) do {                                                         \
    _Pragma("unroll")                                                             \
    for (int i = 0; i < 4; ++i)                                                   \
        __builtin_amdgcn_global_load_lds(GPTR(gA[i] + (K0)),                      \
                                         LPTR(&As[B][dA[i]]), 16, 0, 0);          \
    _Pragma("unroll")                                                             \
    for (int i = 0; i < 2; ++i) {                                                 \
        __builtin_amdgcn_global_load_lds(GPTR(gW[i] + (K0)),                      \
                                         LPTR(&Ws[B][dW[i]]), 16, 0, 0);          \
        __builtin_amdgcn_global_load_lds(GPTR(gG[i] + (K0)),                      \
                                         LPTR(&Gs[B][dW[i]]), 16, 0, 0);          \
    }                                                                             \
} while (0)

    // 24 ds_read_b128 + 64 MFMA per K-tile per wave (same j/quad walk as R7
    // -> identical summation order -> identical numerics)
#define COMPUTE(B) do {                                                           \
    _Pragma("unroll")                                                             \
    for (int j = 0; j < 2; ++j) {                                                 \
        const int kc = ((j * 4 + quad) ^ (fr & 7)) * 8;                           \
        short8 af[4], wf[4], gf[4];                                               \
        _Pragma("unroll")                                                         \
        for (int mt = 0; mt < 4; ++mt)                                            \
            af[mt] = *(const short8*)(&As[B][(wm + mt * 16 + fr) * BK + kc]);     \
        _Pragma("unroll")                                                         \
        for (int nt = 0; nt < 4; ++nt) {                                          \
            wf[nt] = *(const short8*)(&Ws[B][(wn + nt * 16 + fr) * BK + kc]);     \
            gf[nt] = *(const short8*)(&Gs[B][(wn + nt * 16 + fr) * BK + kc]);     \
        }                                                                         \
        __builtin_amdgcn_s_setprio(1);                                            \
        _Pragma("unroll")                                                         \
        for (int mt = 0; mt < 4; ++mt)                                            \
            _Pragma("unroll")                                                     \
            for (int nt = 0; nt < 4; ++nt) {                                      \
                accB[mt][nt] = __builtin_amdgcn_mfma_f32_16x16x32_bf16(           \
                    af[mt], wf[nt], accB[mt][nt], 0, 0, 0);                       \
                accP[mt][nt] = __builtin_amdgcn_mfma_f32_16x16x32_bf16(           \
                    af[mt], gf[nt], accP[mt][nt], 0, 0, 0);                       \
            }                                                                     \
        __builtin_amdgcn_s_setprio(0);                                            \
    }                                                                             \
} while (0)

    // counted waitcnt, fenced against compiler motion (rule #18 insurance)
#define WAITV(N) do {                                                             \
    __builtin_amdgcn_sched_barrier(0);                                            \
    asm volatile("s_waitcnt vmcnt(" #N ")" ::: "memory");                         \
    __builtin_amdgcn_sched_barrier(0);                                            \
} while (0)

    // prologue: tiles 0 and 1 in flight; wait for tile 0 only (oldest 8)
    STAGE(0, 0);
    STAGE(1, BK);
    WAITV(8);
    __builtin_amdgcn_s_barrier();

    // steady state: 8 loads (next-next tile) in flight across every barrier.
    // barrier A: all waves done READING buf[cur] -> safe to overwrite.
    // vmcnt(8): the 8 loads issued ONE TILE AGO (for buf[nxt]) have landed;
    // the 8 just issued remain outstanding. barrier B: publish to all waves.
#pragma unroll 1
    for (int tt = 0; tt < NT - 2; tt += 2) {
        COMPUTE(0);
        __builtin_amdgcn_s_barrier();
        STAGE(0, (tt + 2) * BK);
        WAITV(8);
        __builtin_amdgcn_s_barrier();

        COMPUTE(1);
        __builtin_amdgcn_s_barrier();
        STAGE(1, (tt + 3) * BK);
        WAITV(8);
        __builtin_amdgcn_s_barrier();
    }

    // tail: tile 30 (buf0), drain tile 31's loads, tile 31 (buf1)
    COMPUTE(0);
    __builtin_amdgcn_s_barrier();
    WAITV(0);
    __builtin_amdgcn_s_barrier();
    COMPUTE(1);

#undef STAGE
#undef COMPUTE
#undef WAITV

    // --- epilogue: out = base + bias[n] - lr[m]*(pert + bgrad[n]) ---
    // C/D layout: col = lane&15, row = quad*4 + reg  (verified R2-R7)
    const int col = fr;
    const int gmb = by * BM + wm;
    const int gnb = bx * BN + wn;

    float lrv[4][4];
#pragma unroll
    for (int mt = 0; mt < 4; ++mt)
#pragma unroll
        for (int i = 0; i < 4; ++i)
            lrv[mt][i] = lr[gmb + mt * 16 + quad * 4 + i];

#pragma unroll
    for (int nt = 0; nt < 4; ++nt) {
        const int gn = gnb + nt * 16 + col;
        const float bn = bias[gn];
        const float bg = bgrad[gn];
#pragma unroll
        for (int mt = 0; mt < 4; ++mt) {
#pragma unroll
            for (int i = 0; i < 4; ++i) {
                const int gm = gmb + mt * 16 + quad * 4 + i;
                float v = accB[mt][nt][i] + bn - lrv[mt][i] * (accP[mt][nt][i] + bg);
                __builtin_nontemporal_store(v, out + (size_t)gm * Ndim + gn);
            }
        }
    }
}

extern "C" void kernel_launch(void* const* d_in, const int* in_sizes, int n_in,
                              void* d_out, int out_size, void* d_ws, size_t ws_size,
                              hipStream_t stream) {
    const float* x     = (const float*)d_in[0];  // [4096, 2048]
    const float* W     = (const float*)d_in[1];  // [2048, 2048]
    const float* bias  = (const float*)d_in[2];  // [2048]
    const float* G     = (const float*)d_in[3];  // [2048, 2048]
    const float* bgrad = (const float*)d_in[4];  // [2048]
    const float* lr    = (const float*)d_in[5];  // [4096]
    float* out = (float*)d_out;

    const int nX = 4096 * 2048;
    const int nW = 2048 * 2048;

    ushort_t* xb = (ushort_t*)d_ws;
    ushort_t* wb = xb + nX;
    ushort_t* gb = wb + nW;

    const int uX = nX / 8, uW = nW / 8;
    const int totalU = uX + 2 * uW;               // 2,097,152
    cvt_all_kernel<<<totalU / 256, 256, 0, stream>>>(x, W, G, xb, wb, gb, uX, uW);

    dim3 grid(16, 16);   // N tiles x M tiles = 256 blocks = 1/CU
    fused_gemm_kernel<<<grid, 512, 0, stream>>>(xb, wb, gb, bias, bgrad, lr, out);
}